// Round 5
// baseline (566.450 us; speedup 1.0000x reference)
//
#include <hip/hip_runtime.h>

#define N_EDGES 3200000
#define N_NODES 100000
#define SFIX 16384.0f
#define INVSFIX 6.103515625e-05f

typedef unsigned short ushort_t;
typedef unsigned long long u64_t;
typedef __attribute__((ext_vector_type(8))) short bf16x8;  // 8 bf16 in 4 VGPRs
typedef __attribute__((ext_vector_type(4))) float f32x4;

// ---------- bf16 helpers ----------
__device__ inline unsigned short f2bf(float f) {
    unsigned u = __float_as_uint(f);
    u += 0x7fffu + ((u >> 16) & 1u);       // round-to-nearest-even
    return (unsigned short)(u >> 16);
}
__device__ inline unsigned pack_bf2(float lo, float hi) {
    return (unsigned)f2bf(lo) | ((unsigned)f2bf(hi) << 16);
}
__device__ inline bf16x8 u4_to_b8(uint4 u) {
    union { uint4 a; bf16x8 b; } c; c.a = u; return c.b;
}
// relu + fixed-point pack of two adjacent features into one u64
__device__ inline u64_t fixpair(float lo, float hi) {
    const unsigned ul = __float2uint_rn(fmaxf(lo, 0.0f) * SFIX);
    const unsigned uh = __float2uint_rn(fmaxf(hi, 0.0f) * SFIX);
    return (u64_t)ul | ((u64_t)uh << 32);
}

// ---------- pass 1: cast/transpose tables + acc64 zeroing (NO GEMMs) ----------
// xb   [N][32]  bf16 node features (the only gathered table, 6.4 MB)
// WaT  [32][32] bf16: WaT[o][k] = We1[k][o]          (x_dst -> h1)
// WbT  [32][32] bf16: WbT[o][k] = We1[32+k][o]       (x_src -> h1)
// WcTp [32][32] bf16: k<6: We1[64+k][o]; k==6: be1[o]; else 0   (xe + bias)
// W2T  [16][32] bf16: o<6: We2[k][o]; else 0         (h1 -> em)
// NaT  [64][32] bf16: NaT[o][k] = Wn1[k][o]          (x_dst -> h2)
// NbTp [64][32] bf16: k<6: Wn1[32+k][o]; k==6: bn1[o]; else 0   (em + bias)
// N2T  [32][64] bf16: N2T[o][k] = Wn2[k][o]          (h2 -> nm)
// be2p [16]     f32 : n<6: be2[n]; else 0
__global__ void __launch_bounds__(256) mpn_precompute(
    const float* __restrict__ x_node,
    const float* __restrict__ We1, const float* __restrict__ be1,
    const float* __restrict__ We2, const float* __restrict__ be2,
    const float* __restrict__ Wn1, const float* __restrict__ bn1,
    const float* __restrict__ Wn2,
    unsigned* __restrict__ xb,
    ushort_t* __restrict__ WaT, ushort_t* __restrict__ WbT,
    ushort_t* __restrict__ WcTp, ushort_t* __restrict__ W2T,
    ushort_t* __restrict__ NaT, ushort_t* __restrict__ NbTp,
    ushort_t* __restrict__ N2T, float* __restrict__ be2p,
    u64_t* __restrict__ acc64)           // zeroed here (fixed-point accumulator)
{
    const int n = blockIdx.x * 256 + threadIdx.x;

    if (n < 1024) {
        const int o = n >> 5, k = n & 31;
        WaT[n] = f2bf(We1[k * 32 + o]);
        WbT[n] = f2bf(We1[(32 + k) * 32 + o]);
        WcTp[n] = (k < 6) ? f2bf(We1[(64 + k) * 32 + o])
                          : ((k == 6) ? f2bf(be1[o]) : (ushort_t)0);
    }
    if (n < 512) {
        const int o = n >> 5, k = n & 31;
        W2T[n] = (o < 6) ? f2bf(We2[k * 6 + o]) : (ushort_t)0;
    }
    if (n < 2048) {
        const int o = n >> 5, k = n & 31;
        NaT[n] = f2bf(Wn1[k * 64 + o]);
        NbTp[n] = (k < 6) ? f2bf(Wn1[(32 + k) * 64 + o])
                          : ((k == 6) ? f2bf(bn1[o]) : (ushort_t)0);
        N2T[n] = f2bf(Wn2[(n & 63) * 32 + (n >> 6)]);   // [o=n>>6][k=n&63]
    }
    if (n < 16) be2p[n] = (n < 6) ? be2[n] : 0.0f;

    if (n >= N_NODES) return;

    // zero the fixed-point accumulator (128 B/node)
    {
        uint4 z = make_uint4(0, 0, 0, 0);
        uint4* a = (uint4*)(acc64 + (size_t)n * 16);
        #pragma unroll
        for (int i = 0; i < 8; ++i) a[i] = z;
    }
    // bf16 node-feature row
    {
        const float4* px = (const float4*)(x_node + (size_t)n * 32);
        unsigned* xr = xb + (size_t)n * 16;
        #pragma unroll
        for (int i = 0; i < 8; ++i) {
            float4 v = px[i];
            xr[2*i+0] = pack_bf2(v.x, v.y);
            xr[2*i+1] = pack_bf2(v.z, v.w);
        }
    }
}

// ---------- pass 2: all-MFMA transposed pipeline, 128 edges/block ----------
// Per wave: 32 edges as 2 n-tiles of 16. Everything computed as
// C^T (col = edge = l15, row = feature = q*4+r per 16-row m-tile);
// C->B fragment conversion between layers via in-register shuffles.
// Epilogue: packed fixed-point u64 atomics (2 feats/op) -> 51.2M ops total.
__global__ void __launch_bounds__(256, 4) mpn_main(
    const ushort_t* __restrict__ xb,
    const ushort_t* __restrict__ WaT, const ushort_t* __restrict__ WbT,
    const ushort_t* __restrict__ WcTp, const ushort_t* __restrict__ W2T,
    const ushort_t* __restrict__ NaT, const ushort_t* __restrict__ NbTp,
    const ushort_t* __restrict__ N2T,
    const float* __restrict__ be2p, const float* __restrict__ bn2,
    const float* __restrict__ x_edge,
    const int* __restrict__ src, const int* __restrict__ dst,
    u64_t* __restrict__ acc64,    // [N_NODES, 16] packed fixed-point
    float* __restrict__ em_out)   // [N_EDGES, 6]
{
    __shared__ u64_t s_a64[128 * 16];      // 16384 B staged fixed-point rows
    __shared__ int s_d[128];

    const int tid  = threadIdx.x;
    const int lane = tid & 63;
    const int wave = tid >> 6;
    const int q    = (lane >> 4) & 3;
    const int l15  = lane & 15;
    const int hi   = q >> 1;

    const int eb = blockIdx.x * 128 + wave * 32;

    // ---- hoisted gathers for both sub-tiles (all latency in flight together)
    int dv[2], sv[2];
    #pragma unroll
    for (int t = 0; t < 2; ++t) {
        const int e = eb + t * 16 + l15;
        dv[t] = dst[e];
        sv[t] = src[e];
    }
    bf16x8 xd[2], xs[2];
    #pragma unroll
    for (int t = 0; t < 2; ++t) {
        xd[t] = *(const bf16x8*)(xb + (size_t)dv[t] * 32 + q * 8);  // B[edge][k]
        xs[t] = *(const bf16x8*)(xb + (size_t)sv[t] * 32 + q * 8);
    }
    uint4 bxeU[2];
    #pragma unroll
    for (int t = 0; t < 2; ++t) {
        uint4 u = make_uint4(0, 0, 0, 0);
        if (q == 0) {   // only k=0..7 lanes carry xe (k6 = 1.0 -> be1 fold)
            const int e = eb + t * 16 + l15;
            const float2* pe = (const float2*)(x_edge + (size_t)e * 6);
            float2 a = pe[0], b = pe[1], c = pe[2];
            u = make_uint4(pack_bf2(a.x, a.y), pack_bf2(b.x, b.y),
                           pack_bf2(c.x, c.y), pack_bf2(1.0f, 0.0f));
        }
        bxeU[t] = u;
    }

    const int sAl = ((q & 1) << 5) + l15;   // src lane for k-low half
    const int sBl = sAl + 16;               // src lane for k-high half

    #pragma unroll
    for (int t = 0; t < 2; ++t) {
        // ---- h1^T = relu(WaT·xd + WbT·xs + WcTp·xe)   [32 x 16e]
        f32x4 h1c[2];
        #pragma unroll
        for (int m = 0; m < 2; ++m) {
            const int row = m * 16 + l15;
            f32x4 acc = (f32x4)0.f;
            acc = __builtin_amdgcn_mfma_f32_16x16x32_bf16(
                *(const bf16x8*)(WaT + row * 32 + q * 8), xd[t], acc, 0, 0, 0);
            acc = __builtin_amdgcn_mfma_f32_16x16x32_bf16(
                *(const bf16x8*)(WbT + row * 32 + q * 8), xs[t], acc, 0, 0, 0);
            acc = __builtin_amdgcn_mfma_f32_16x16x32_bf16(
                *(const bf16x8*)(WcTp + row * 32 + q * 8), u4_to_b8(bxeU[t]), acc, 0, 0, 0);
            #pragma unroll
            for (int r = 0; r < 4; ++r) acc[r] = fmaxf(acc[r], 0.f);
            h1c[m] = acc;
        }

        // ---- C->B: lane needs h1[edge=l15][k=q*8+j]
        unsigned u00 = pack_bf2(h1c[0][0], h1c[0][1]);
        unsigned u01 = pack_bf2(h1c[0][2], h1c[0][3]);
        unsigned u10 = pack_bf2(h1c[1][0], h1c[1][1]);
        unsigned u11 = pack_bf2(h1c[1][2], h1c[1][3]);
        unsigned a0 = __shfl((int)u00, sAl), a1 = __shfl((int)u01, sAl);
        unsigned a2 = __shfl((int)u10, sAl), a3 = __shfl((int)u11, sAl);
        unsigned b0 = __shfl((int)u00, sBl), b1 = __shfl((int)u01, sBl);
        unsigned b2 = __shfl((int)u10, sBl), b3 = __shfl((int)u11, sBl);
        uint4 bh1 = make_uint4(hi ? a2 : a0, hi ? a3 : a1,
                               hi ? b2 : b0, hi ? b3 : b1);

        // ---- em^T = W2T · h1^T   [16(6 valid) x 16e]
        f32x4 emc = __builtin_amdgcn_mfma_f32_16x16x32_bf16(
            *(const bf16x8*)(W2T + l15 * 32 + q * 8), u4_to_b8(bh1),
            (f32x4)0.f, 0, 0, 0);
        const float emv0 = fmaxf(emc[0] + be2p[q * 4 + 0], 0.f);
        const float emv1 = fmaxf(emc[1] + be2p[q * 4 + 1], 0.f);
        const float emv2 = fmaxf(emc[2] + be2p[q * 4 + 2], 0.f);
        const float emv3 = fmaxf(emc[3] + be2p[q * 4 + 3], 0.f);

        // em_out: q0 holds feats 0-3, q1 holds feats 4-5 (rows 4,5)
        const int e = eb + t * 16 + l15;
        if (q == 0) {
            *(float2*)(em_out + (size_t)e * 6 + 0) = make_float2(emv0, emv1);
            *(float2*)(em_out + (size_t)e * 6 + 2) = make_float2(emv2, emv3);
        } else if (q == 1) {
            *(float2*)(em_out + (size_t)e * 6 + 4) = make_float2(emv0, emv1);
        }

        // ---- C->B for h2: em[edge][k<6], k6 = 1.0 (bn1 fold)
        const float f4 = __shfl(emv0, l15 + 16);   // feat 4 from q=1
        const float f5 = __shfl(emv1, l15 + 16);   // feat 5 from q=1
        uint4 bem = make_uint4(0, 0, 0, 0);
        if (q == 0)
            bem = make_uint4(pack_bf2(emv0, emv1), pack_bf2(emv2, emv3),
                             pack_bf2(f4, f5), pack_bf2(1.0f, 0.0f));

        // ---- h2^T = relu(NbTp·em + NaT·xd)   [64 x 16e]
        f32x4 h2c[4];
        #pragma unroll
        for (int m = 0; m < 4; ++m) {
            const int row = m * 16 + l15;
            f32x4 acc = __builtin_amdgcn_mfma_f32_16x16x32_bf16(
                *(const bf16x8*)(NbTp + row * 32 + q * 8), u4_to_b8(bem),
                (f32x4)0.f, 0, 0, 0);
            acc = __builtin_amdgcn_mfma_f32_16x16x32_bf16(
                *(const bf16x8*)(NaT + row * 32 + q * 8), xd[t], acc, 0, 0, 0);
            #pragma unroll
            for (int r = 0; r < 4; ++r) acc[r] = fmaxf(acc[r], 0.f);
            h2c[m] = acc;
        }

        // ---- C->B for nm: lane needs h2[edge][k = kt*32 + q*8 + j]
        unsigned v00 = pack_bf2(h2c[0][0], h2c[0][1]), v01 = pack_bf2(h2c[0][2], h2c[0][3]);
        unsigned v10 = pack_bf2(h2c[1][0], h2c[1][1]), v11 = pack_bf2(h2c[1][2], h2c[1][3]);
        unsigned v20 = pack_bf2(h2c[2][0], h2c[2][1]), v21 = pack_bf2(h2c[2][2], h2c[2][3]);
        unsigned v30 = pack_bf2(h2c[3][0], h2c[3][1]), v31 = pack_bf2(h2c[3][2], h2c[3][3]);
        unsigned c0 = __shfl((int)v00, sAl), c1 = __shfl((int)v01, sAl);
        unsigned c2 = __shfl((int)v10, sAl), c3 = __shfl((int)v11, sAl);
        unsigned d0 = __shfl((int)v00, sBl), d1 = __shfl((int)v01, sBl);
        unsigned d2 = __shfl((int)v10, sBl), d3 = __shfl((int)v11, sBl);
        uint4 bh2k0 = make_uint4(hi ? c2 : c0, hi ? c3 : c1,
                                 hi ? d2 : d0, hi ? d3 : d1);
        unsigned g0 = __shfl((int)v20, sAl), g1 = __shfl((int)v21, sAl);
        unsigned g2 = __shfl((int)v30, sAl), g3 = __shfl((int)v31, sAl);
        unsigned k0 = __shfl((int)v20, sBl), k1 = __shfl((int)v21, sBl);
        unsigned k2 = __shfl((int)v30, sBl), k3 = __shfl((int)v31, sBl);
        uint4 bh2k1 = make_uint4(hi ? g2 : g0, hi ? g3 : g1,
                                 hi ? k2 : k0, hi ? k3 : k1);

        // ---- nm^T = N2T · h2^T   [32 x 16e]
        f32x4 nm0 = __builtin_amdgcn_mfma_f32_16x16x32_bf16(
            *(const bf16x8*)(N2T + (0 * 16 + l15) * 64 + q * 8), u4_to_b8(bh2k0),
            (f32x4)0.f, 0, 0, 0);
        nm0 = __builtin_amdgcn_mfma_f32_16x16x32_bf16(
            *(const bf16x8*)(N2T + (0 * 16 + l15) * 64 + 32 + q * 8), u4_to_b8(bh2k1),
            nm0, 0, 0, 0);
        f32x4 nm1 = __builtin_amdgcn_mfma_f32_16x16x32_bf16(
            *(const bf16x8*)(N2T + (1 * 16 + l15) * 64 + q * 8), u4_to_b8(bh2k0),
            (f32x4)0.f, 0, 0, 0);
        nm1 = __builtin_amdgcn_mfma_f32_16x16x32_bf16(
            *(const bf16x8*)(N2T + (1 * 16 + l15) * 64 + 32 + q * 8), u4_to_b8(bh2k1),
            nm1, 0, 0, 0);

        // ---- stage relu(nm + bn2) as packed fixed-point u64 (feats 2j, 2j+1)
        // nm0 reg r = feat q*4+r  -> pairs j = q*2, q*2+1
        // nm1 reg r = feat 16+q*4+r -> pairs j = 8+q*2, 8+q*2+1
        {
            const int row = wave * 32 + t * 16 + l15;
            u64_t* sr = s_a64 + row * 16;
            const int f = q * 4;
            sr[q*2 + 0]     = fixpair(nm0[0] + bn2[f+0], nm0[1] + bn2[f+1]);
            sr[q*2 + 1]     = fixpair(nm0[2] + bn2[f+2], nm0[3] + bn2[f+3]);
            sr[8 + q*2 + 0] = fixpair(nm1[0] + bn2[16+f+0], nm1[1] + bn2[16+f+1]);
            sr[8 + q*2 + 1] = fixpair(nm1[2] + bn2[16+f+2], nm1[3] + bn2[16+f+3]);
        }
        if (q == 0) s_d[wave * 32 + t * 16 + l15] = dv[t];
    }
    __syncthreads();

    // ---- coalesced u64 atomic segment-sum: 128 rows x 16 u64, 1 op each
    #pragma unroll 4
    for (int it = 0; it < 8; ++it) {
        const int idx = it * 256 + tid;
        const int row = idx >> 4;
        const int j   = idx & 15;
        atomicAdd(acc64 + (size_t)s_d[row] * 16 + j, s_a64[row * 16 + j]);
    }
}

// ---------- pass 3: fixed-point -> f32 output ----------
__global__ void __launch_bounds__(256) mpn_convert(
    const u64_t* __restrict__ acc64,
    float* __restrict__ nm_out)
{
    const int n = blockIdx.x * 256 + threadIdx.x;
    if (n >= N_NODES) return;
    const u64_t* a = acc64 + (size_t)n * 16;
    float4* o = (float4*)(nm_out + (size_t)n * 32);
    #pragma unroll
    for (int i = 0; i < 8; ++i) {
        const u64_t v0 = a[2*i], v1 = a[2*i+1];
        o[i] = make_float4((float)(unsigned)v0         * INVSFIX,
                           (float)(unsigned)(v0 >> 32) * INVSFIX,
                           (float)(unsigned)v1         * INVSFIX,
                           (float)(unsigned)(v1 >> 32) * INVSFIX);
    }
}

extern "C" void kernel_launch(void* const* d_in, const int* in_sizes, int n_in,
                              void* d_out, int out_size, void* d_ws, size_t ws_size,
                              hipStream_t stream) {
    const float* x_node = (const float*)d_in[0];
    const float* x_edge = (const float*)d_in[1];
    const int*   src    = (const int*)d_in[2];
    const int*   dst    = (const int*)d_in[3];
    const float* We1 = (const float*)d_in[4];
    const float* be1 = (const float*)d_in[5];
    const float* We2 = (const float*)d_in[6];
    const float* be2 = (const float*)d_in[7];
    const float* Wn1 = (const float*)d_in[8];
    const float* bn1 = (const float*)d_in[9];
    const float* Wn2 = (const float*)d_in[10];
    const float* bn2 = (const float*)d_in[11];

    float* nm_out = (float*)d_out;                        // [N_NODES*32]
    float* em_out = (float*)d_out + (size_t)N_NODES * 32; // [N_EDGES*6]

    // workspace layout (bytes):
    //   xb    @ 0        : 100000*64 = 6,400,000
    //   WaT   @ 6400000  : 2048
    //   WbT   @ 6402048  : 2048
    //   WcTp  @ 6404096  : 2048
    //   W2T   @ 6406144  : 1024
    //   NaT   @ 6407168  : 4096
    //   NbTp  @ 6411264  : 4096
    //   N2T   @ 6415360  : 4096
    //   be2p  @ 6419456  : 64
    //   acc64 @ 6420480  : 100000*16*8 = 12,800,000   (8B aligned)
    char* ws = (char*)d_ws;
    unsigned* xb    = (unsigned*)ws;
    ushort_t* WaT   = (ushort_t*)(ws + 6400000);
    ushort_t* WbT   = (ushort_t*)(ws + 6402048);
    ushort_t* WcTp  = (ushort_t*)(ws + 6404096);
    ushort_t* W2T   = (ushort_t*)(ws + 6406144);
    ushort_t* NaT   = (ushort_t*)(ws + 6407168);
    ushort_t* NbTp  = (ushort_t*)(ws + 6411264);
    ushort_t* N2T   = (ushort_t*)(ws + 6415360);
    float*    be2p  = (float*)(ws + 6419456);
    u64_t*    acc64 = (u64_t*)(ws + 6420480);

    mpn_precompute<<<(N_NODES + 255) / 256, 256, 0, stream>>>(
        x_node, We1, be1, We2, be2, Wn1, bn1, Wn2,
        xb, WaT, WbT, WcTp, W2T, NaT, NbTp, N2T, be2p, acc64);

    mpn_main<<<N_EDGES / 128, 256, 0, stream>>>(
        (const ushort_t*)xb, WaT, WbT, WcTp, W2T, NaT, NbTp, N2T,
        be2p, bn2, x_edge, src, dst, acc64, em_out);

    mpn_convert<<<(N_NODES + 255) / 256, 256, 0, stream>>>(acc64, nm_out);
}